// Round 1
// baseline (169.725 us; speedup 1.0000x reference)
//
#include <hip/hip_runtime.h>
#include <math.h>

#define D_DIM 2048
#define M_EV  16384
#define LCH   32
#define CCH   (M_EV / LCH)      // 512 chunks
#define BETA  1.0f

__device__ __forceinline__ float softplus_f(float x){
  float e = __expf(-fabsf(x));
  return fmaxf(x, 0.0f) + __logf(1.0f + e);
}

// T_max arrives as a 1-element array; dtype (int vs float) is ambiguous for a
// Python scalar. Decode defensively: a float32 bit pattern for a sane T lands
// in [1e-3, 1e7]; an int 100 reinterpreted as float is denormal-tiny.
__device__ __forceinline__ float decode_T(const void* p){
  unsigned bits = *(const unsigned*)p;
  float fv = __uint_as_float(bits);
  return (fv >= 1e-3f && fv <= 1e7f) ? fv : (float)(int)bits;
}

__device__ __forceinline__ float wave_red(float v){
  #pragma unroll
  for (int o = 32; o > 0; o >>= 1) v += __shfl_down(v, o);
  return v;
}

// muw[j] = softplus(log_mu[j]) + 1e-6 ; acc[2] += sum(mu)
__global__ void k_mu(const float* __restrict__ log_mu, float* __restrict__ muw,
                     float* __restrict__ acc){
  int j = blockIdx.x * blockDim.x + threadIdx.x;
  float v = softplus_f(log_mu[j]) + 1e-6f;
  muw[j] = v;
  float s = wave_red(v);
  if ((threadIdx.x & 63) == 0) atomicAdd(&acc[2], s);
}

// contrib[m_i] += 1 - exp(-beta*(T - t_i))   (segment_sum)
__global__ void k_contrib(const float* __restrict__ t, const int* __restrict__ m,
                          const void* Tp, float* __restrict__ contrib){
  int i = blockIdx.x * blockDim.x + threadIdx.x;
  float T = decode_T(Tp);
  float v = 1.0f - __expf(-BETA * (T - t[i]));
  atomicAdd(&contrib[m[i]], v);
}

// acc[1] += sum_{d,j} softplus(log_alpha[d,j]) * contrib[j]
// (sum_d of alpha @ v equals colsum(alpha) . v — no GEMV needed)
__global__ void k_int_alpha(const float* __restrict__ la,
                            const float* __restrict__ contrib,
                            float* __restrict__ acc){
  const int nthreads = gridDim.x * blockDim.x;      // 131072
  int tid = blockIdx.x * blockDim.x + threadIdx.x;
  const float4* la4 = (const float4*)la;
  float p = 0.f;
  #pragma unroll
  for (int u = 0; u < 8; ++u){
    int i4 = tid + u * nthreads;                    // < D*D/4, coalesced
    float4 x = la4[i4];
    int col = (i4 * 4) & (D_DIM - 1);
    p = fmaf(softplus_f(x.x), contrib[col+0], p);
    p = fmaf(softplus_f(x.y), contrib[col+1], p);
    p = fmaf(softplus_f(x.z), contrib[col+2], p);
    p = fmaf(softplus_f(x.w), contrib[col+3], p);
  }
  __shared__ float red[4];
  float w = wave_red(p);
  int lane = threadIdx.x & 63, wid = threadIdx.x >> 6;
  if (lane == 0) red[wid] = w;
  __syncthreads();
  if (threadIdx.x == 0) atomicAdd(&acc[1], red[0]+red[1]+red[2]+red[3]);
}

// dchunk[c] = decay factor from chunk-c start to chunk-(c+1) start
__global__ void k_meta(const float* __restrict__ t, float* __restrict__ dchunk){
  int c = blockIdx.x * blockDim.x + threadIdx.x;
  if (c >= CCH) return;
  dchunk[c] = (c < CCH-1) ? __expf(-BETA * (t[(c+1)*LCH] - t[c*LCH])) : 1.0f;
}

// Lsum[c][j] = sum_{i in chunk c, m_i=j} exp(-beta*(t_{(c+1)L} - t_i))
__global__ void k_lsum(const float* __restrict__ t, const int* __restrict__ m,
                       float* __restrict__ SL){
  int i = blockIdx.x * blockDim.x + threadIdx.x;
  int c = i >> 5;                                   // i / LCH
  if (c >= CCH - 1) return;                         // last chunk carry unused
  float tn = t[(c+1)*LCH];
  float v = __expf(-BETA * (tn - t[i]));
  atomicAdd(&SL[(size_t)c * D_DIM + m[i]], v);
}

// In-place scan over chunks: SL[c][j] becomes S^c_j (state at chunk-c start).
// Per-j chain: S^{c+1} = dchunk[c]*S^c + Lsum[c]. Double-buffered prefetch
// hides the global-load latency of the 512-step chain.
__global__ void k_scan(float* __restrict__ SL, const float* __restrict__ dchunk){
  int j = blockIdx.x * blockDim.x + threadIdx.x;
  float s = 0.f;
  float cur[8], nxt[8];
  #pragma unroll
  for (int u = 0; u < 8; ++u) cur[u] = SL[(size_t)u * D_DIM + j];
  for (int c0 = 0; c0 < CCH; c0 += 8){
    #pragma unroll
    for (int u = 0; u < 8; ++u)
      nxt[u] = (c0 + 8 < CCH) ? SL[(size_t)(c0+8+u) * D_DIM + j] : 0.f;
    #pragma unroll
    for (int u = 0; u < 8; ++u){
      int c = c0 + u;
      float l = cur[u];
      SL[(size_t)c * D_DIM + j] = s;                // store S^c, then advance
      s = fmaf(dchunk[c], s, l);
    }
    #pragma unroll
    for (int u = 0; u < 8; ++u) cur[u] = nxt[u];
  }
}

// One block per chunk: replay the 32 chunk events with S in LDS.
// Thread t owns columns [8t, 8t+8) of S — no cross-thread S hazard; the only
// barrier is the per-event block reduction for log(lam).
__global__ __launch_bounds__(256) void k_events(
    const float* __restrict__ t, const int* __restrict__ m,
    const float* __restrict__ la, const float* __restrict__ muw,
    const float* __restrict__ SL, float* __restrict__ acc){
  __shared__ float S[D_DIM];
  __shared__ float tl[LCH];
  __shared__ int   ml[LCH];
  __shared__ float red[4];
  const int tid = threadIdx.x;
  const int c = blockIdx.x;
  float4* S4 = (float4*)S;
  const float4* src = (const float4*)(SL + (size_t)c * D_DIM);
  S4[tid]       = src[tid];
  S4[tid + 256] = src[tid + 256];
  if (tid < LCH){ tl[tid] = t[c*LCH + tid]; ml[tid] = m[c*LCH + tid]; }
  __syncthreads();
  float logacc = 0.f;
  const int lane = tid & 63, wid = tid >> 6;
  #pragma unroll 1
  for (int k = 0; k < LCH; ++k){
    int d = ml[k];
    float dtk = (k == 0) ? 0.f : (tl[k] - tl[k-1]);   // S^c is already at t_{cL}
    float dec = __expf(-BETA * dtk);
    const float* Ar = la + (size_t)d * D_DIM + tid * 8;
    float4 a0 = *(const float4*)Ar;
    float4 a1 = *(const float4*)(Ar + 4);
    float4 s0 = S4[2*tid], s1 = S4[2*tid+1];
    s0.x *= dec; s0.y *= dec; s0.z *= dec; s0.w *= dec;
    s1.x *= dec; s1.y *= dec; s1.z *= dec; s1.w *= dec;
    float p = 0.f;
    p = fmaf(softplus_f(a0.x), s0.x, p);
    p = fmaf(softplus_f(a0.y), s0.y, p);
    p = fmaf(softplus_f(a0.z), s0.z, p);
    p = fmaf(softplus_f(a0.w), s0.w, p);
    p = fmaf(softplus_f(a1.x), s1.x, p);
    p = fmaf(softplus_f(a1.y), s1.y, p);
    p = fmaf(softplus_f(a1.z), s1.z, p);
    p = fmaf(softplus_f(a1.w), s1.w, p);
    S4[2*tid] = s0; S4[2*tid+1] = s1;
    if ((d >> 3) == tid) S[d] += 1.0f;                // self-excitation bump
    float w = wave_red(p);
    if (lane == 0) red[wid] = w;
    __syncthreads();
    if (tid == 0){
      float lam = muw[d] + red[0] + red[1] + red[2] + red[3];
      logacc += __logf(lam + 1e-8f);
    }
    __syncthreads();
  }
  if (tid == 0) atomicAdd(&acc[0], logacc);
}

__global__ void k_final(const float* __restrict__ acc, const void* Tp,
                        float* __restrict__ out){
  float T = decode_T(Tp);
  out[0] = acc[0] - (T * acc[2] + acc[1] * (1.0f / BETA));
}

extern "C" void kernel_launch(void* const* d_in, const int* in_sizes, int n_in,
                              void* d_out, int out_size, void* d_ws, size_t ws_size,
                              hipStream_t stream) {
  const float* t_events  = (const float*)d_in[0];
  const int*   marks     = (const int*)  d_in[1];
  const void*  Tp        =               d_in[2];
  const float* log_mu    = (const float*)d_in[3];
  const float* log_alpha = (const float*)d_in[4];
  float* out = (float*)d_out;

  // ws layout (floats): SL[C*D] | contrib[D] | acc[16] | muw[D] | dchunk[C]
  float* ws      = (float*)d_ws;
  float* SL      = ws;
  float* contrib = SL + (size_t)CCH * D_DIM;
  float* acc     = contrib + D_DIM;
  float* muw     = acc + 16;
  float* dchunk  = muw + D_DIM;

  size_t zero_floats = (size_t)CCH * D_DIM + D_DIM + 16; // SL+contrib+acc
  hipMemsetAsync(d_ws, 0, zero_floats * sizeof(float), stream);

  k_mu       <<<D_DIM/256, 256, 0, stream>>>(log_mu, muw, acc);
  k_contrib  <<<M_EV/256,  256, 0, stream>>>(t_events, marks, Tp, contrib);
  k_int_alpha<<<512,       256, 0, stream>>>(log_alpha, contrib, acc);
  k_meta     <<<(CCH+255)/256, 256, 0, stream>>>(t_events, dchunk);
  k_lsum     <<<M_EV/256,  256, 0, stream>>>(t_events, marks, SL);
  k_scan     <<<D_DIM/256, 256, 0, stream>>>(SL, dchunk);
  k_events   <<<CCH,       256, 0, stream>>>(t_events, marks, log_alpha, muw, SL, acc);
  k_final    <<<1, 1,      0, stream>>>(acc, Tp, out);
}

// Round 2
// 126.825 us; speedup vs baseline: 1.3383x; 1.3383x over previous
//
#include <hip/hip_runtime.h>
#include <math.h>

#define D_DIM 2048
#define M_EV  16384
#define LCH   32
#define CCH   (M_EV / LCH)      // 512 chunks
#define SEG   32                // chunks per scan segment
#define NSEG  (CCH / SEG)       // 16 segments
#define BETA  1.0f

__device__ __forceinline__ float softplus_f(float x){
  float e = __expf(-fabsf(x));
  return fmaxf(x, 0.0f) + __logf(1.0f + e);
}

// T_max arrives as a 1-element array; decode int-vs-float defensively.
__device__ __forceinline__ float decode_T(const void* p){
  unsigned bits = *(const unsigned*)p;
  float fv = __uint_as_float(bits);
  return (fv >= 1e-3f && fv <= 1e7f) ? fv : (float)(int)bits;
}

__device__ __forceinline__ float wave_red(float v){
  #pragma unroll
  for (int o = 32; o > 0; o >>= 1) v += __shfl_down(v, o);
  return v;
}

// Fused small-work kernel. Block ranges:
//   [0,8)     : muw[j] = softplus(log_mu)+eps ; acc[2] += sum(mu)
//   [8,72)    : contrib[m_i] += 1-exp(-beta*(T-t_i))
//   [72,136)  : Lsum scatter: SL[c][m_i] += exp(-beta*(t_{(c+1)L}-t_i))
//   [136,138) : dchunk/cumdec per chunk (+ Aseg per segment in block 136)
__global__ void k_small(const float* __restrict__ t, const int* __restrict__ m,
                        const void* Tp, const float* __restrict__ log_mu,
                        float* __restrict__ muw, float* __restrict__ contrib,
                        float* __restrict__ SL, float* __restrict__ dchunk,
                        float* __restrict__ cumdec, float* __restrict__ Aseg,
                        float* __restrict__ acc){
  const int b = blockIdx.x, tid = threadIdx.x;
  if (b < 8){
    int j = b*256 + tid;
    float v = softplus_f(log_mu[j]) + 1e-6f;
    muw[j] = v;
    float s = wave_red(v);
    if ((tid & 63) == 0) atomicAdd(&acc[2], s);
  } else if (b < 72){
    int i = (b-8)*256 + tid;
    float T = decode_T(Tp);
    float v = 1.0f - __expf(-BETA * (T - t[i]));
    atomicAdd(&contrib[m[i]], v);
  } else if (b < 136){
    int i = (b-72)*256 + tid;
    int c = i >> 5;
    if (c < CCH - 1){                       // last chunk's carry is unused
      float tn = t[(c+1)*LCH];
      float v = __expf(-BETA * (tn - t[i]));
      atomicAdd(&SL[(size_t)c * D_DIM + m[i]], v);
    }
  } else {
    int c = (b-136)*256 + tid;              // c in [0,512)
    float tc = t[c*LCH];
    dchunk[c] = (c < CCH-1) ? __expf(-BETA * (t[(c+1)*LCH] - tc)) : 1.0f;
    int s0c = (c >> 5) << 5;                // segment-start chunk
    cumdec[c] = __expf(-BETA * (tc - t[s0c*LCH]));
    if (b == 136 && tid < NSEG){
      int s = tid;
      Aseg[s] = (s < NSEG-1)
        ? __expf(-BETA * (t[(s+1)*SEG*LCH] - t[s*SEG*LCH])) : 1.0f;
    }
  }
}

// Local exclusive scan within each segment (in-place), carry-out per segment.
// Grid: NSEG*8 = 128 blocks; thread handles one column j over 32 chunks.
__global__ void k_scan_local(float* __restrict__ SL,
                             const float* __restrict__ dchunk,
                             float* __restrict__ Carry){
  const int tid = threadIdx.x;
  const int seg = blockIdx.x >> 3, jb = blockIdx.x & 7;
  const int j = jb*256 + tid;
  const int c0 = seg * SEG;
  const size_t base = (size_t)c0 * D_DIM + j;
  float u = 0.f;
  float cur[4], nxt[4];
  #pragma unroll
  for (int q = 0; q < 4; ++q) cur[q] = SL[base + (size_t)q * D_DIM];
  for (int g = 0; g < SEG; g += 4){
    #pragma unroll
    for (int q = 0; q < 4; ++q)
      nxt[q] = (g+4 < SEG) ? SL[base + (size_t)(g+4+q) * D_DIM] : 0.f;
    #pragma unroll
    for (int q = 0; q < 4; ++q){
      int c = c0 + g + q;
      float l = cur[q];
      SL[(size_t)c * D_DIM + j] = u;
      u = fmaf(dchunk[c], u, l);
    }
    #pragma unroll
    for (int q = 0; q < 4; ++q) cur[q] = nxt[q];
  }
  Carry[(size_t)seg * D_DIM + j] = u;
}

// Scan segment carries: E[s][j] = state entering segment s. 16 affine steps.
__global__ void k_scan_carry(const float* __restrict__ Carry,
                             const float* __restrict__ Aseg,
                             float* __restrict__ E){
  const int j = blockIdx.x*256 + threadIdx.x;
  float cr[NSEG];
  #pragma unroll
  for (int s = 0; s < NSEG; ++s) cr[s] = Carry[(size_t)s * D_DIM + j];
  float e = 0.f;
  #pragma unroll
  for (int s = 0; s < NSEG; ++s){
    E[(size_t)s * D_DIM + j] = e;
    e = fmaf(Aseg[s], e, cr[s]);
  }
}

// One block per chunk. S entirely in registers (thread owns cols [8t,8t+8)).
// No barriers in the event loop: per-wave dot partials go to red[k][wid];
// log(lam) is deferred to a single pass after the loop.
__global__ __launch_bounds__(256) void k_events(
    const float* __restrict__ t, const int* __restrict__ m,
    const float* __restrict__ la, const float* __restrict__ muw,
    const float* __restrict__ SL, const float* __restrict__ E,
    const float* __restrict__ cumdec, float* __restrict__ acc){
  __shared__ float tl[LCH];
  __shared__ int   ml[LCH];
  __shared__ float red[LCH][4];
  const int tid = threadIdx.x;
  const int c = blockIdx.x;
  const int seg = c >> 5;
  const float cd = cumdec[c];

  const float4* sp = (const float4*)(SL + (size_t)c  * D_DIM + tid*8);
  const float4* ep = (const float4*)(E  + (size_t)seg * D_DIM + tid*8);
  float4 s0 = sp[0], s1 = sp[1];
  float4 e0 = ep[0], e1 = ep[1];
  s0.x = fmaf(e0.x, cd, s0.x); s0.y = fmaf(e0.y, cd, s0.y);
  s0.z = fmaf(e0.z, cd, s0.z); s0.w = fmaf(e0.w, cd, s0.w);
  s1.x = fmaf(e1.x, cd, s1.x); s1.y = fmaf(e1.y, cd, s1.y);
  s1.z = fmaf(e1.z, cd, s1.z); s1.w = fmaf(e1.w, cd, s1.w);

  if (tid < LCH){ tl[tid] = t[c*LCH + tid]; ml[tid] = m[c*LCH + tid]; }
  __syncthreads();

  const int lane = tid & 63, wid = tid >> 6;
  const int colb = tid * 8;

  // prologue: prefetch row for event 0
  const float* A0 = la + (size_t)ml[0] * D_DIM + colb;
  float4 a0 = *(const float4*)A0, a1 = *(const float4*)(A0 + 4);

  #pragma unroll 1
  for (int k = 0; k < LCH; ++k){
    const int d = ml[k];
    // prefetch next event's row (issues early; waited on next iteration)
    const int kn = (k < LCH-1) ? k+1 : k;
    const float* Bp = la + (size_t)ml[kn] * D_DIM + colb;
    float4 b0 = *(const float4*)Bp, b1 = *(const float4*)(Bp + 4);

    const float dec = (k == 0) ? 1.0f : __expf(-BETA * (tl[k] - tl[k-1]));
    s0.x *= dec; s0.y *= dec; s0.z *= dec; s0.w *= dec;
    s1.x *= dec; s1.y *= dec; s1.z *= dec; s1.w *= dec;

    float p = 0.f;
    p = fmaf(softplus_f(a0.x), s0.x, p);
    p = fmaf(softplus_f(a0.y), s0.y, p);
    p = fmaf(softplus_f(a0.z), s0.z, p);
    p = fmaf(softplus_f(a0.w), s0.w, p);
    p = fmaf(softplus_f(a1.x), s1.x, p);
    p = fmaf(softplus_f(a1.y), s1.y, p);
    p = fmaf(softplus_f(a1.z), s1.z, p);
    p = fmaf(softplus_f(a1.w), s1.w, p);

    if ((d >> 3) == tid){                     // self-excitation bump (owner)
      int r = d & 7;
      s0.x += (r==0) ? 1.f : 0.f; s0.y += (r==1) ? 1.f : 0.f;
      s0.z += (r==2) ? 1.f : 0.f; s0.w += (r==3) ? 1.f : 0.f;
      s1.x += (r==4) ? 1.f : 0.f; s1.y += (r==5) ? 1.f : 0.f;
      s1.z += (r==6) ? 1.f : 0.f; s1.w += (r==7) ? 1.f : 0.f;
    }

    float w = wave_red(p);
    if (lane == 0) red[k][wid] = w;           // no barrier needed until end

    a0 = b0; a1 = b1;
  }

  __syncthreads();
  float lg = 0.f;
  if (tid < LCH){
    float lam = muw[ml[tid]] + red[tid][0] + red[tid][1]
                             + red[tid][2] + red[tid][3];
    lg = __logf(lam + 1e-8f);
  }
  if (tid < 64){
    float w = wave_red(lg);
    if (tid == 0) atomicAdd(&acc[0], w);
  }
}

// acc[1] += sum_{d,j} softplus(log_alpha[d,j]) * contrib[j]
__global__ void k_int_alpha(const float* __restrict__ la,
                            const float* __restrict__ contrib,
                            float* __restrict__ acc){
  const int nthreads = gridDim.x * blockDim.x;      // 131072
  int tid = blockIdx.x * blockDim.x + threadIdx.x;
  const float4* la4 = (const float4*)la;
  float p = 0.f;
  #pragma unroll
  for (int u = 0; u < 8; ++u){
    int i4 = tid + u * nthreads;
    float4 x = la4[i4];
    int col = (i4 * 4) & (D_DIM - 1);
    p = fmaf(softplus_f(x.x), contrib[col+0], p);
    p = fmaf(softplus_f(x.y), contrib[col+1], p);
    p = fmaf(softplus_f(x.z), contrib[col+2], p);
    p = fmaf(softplus_f(x.w), contrib[col+3], p);
  }
  __shared__ float red[4];
  float w = wave_red(p);
  int lane = threadIdx.x & 63, wid = threadIdx.x >> 6;
  if (lane == 0) red[wid] = w;
  __syncthreads();
  if (threadIdx.x == 0) atomicAdd(&acc[1], red[0]+red[1]+red[2]+red[3]);
}

__global__ void k_final(const float* __restrict__ acc, const void* Tp,
                        float* __restrict__ out){
  float T = decode_T(Tp);
  out[0] = acc[0] - (T * acc[2] + acc[1] * (1.0f / BETA));
}

extern "C" void kernel_launch(void* const* d_in, const int* in_sizes, int n_in,
                              void* d_out, int out_size, void* d_ws, size_t ws_size,
                              hipStream_t stream) {
  const float* t_events  = (const float*)d_in[0];
  const int*   marks     = (const int*)  d_in[1];
  const void*  Tp        =               d_in[2];
  const float* log_mu    = (const float*)d_in[3];
  const float* log_alpha = (const float*)d_in[4];
  float* out = (float*)d_out;

  // ws layout (floats), zeroed region first:
  // SL[CCH*D] | contrib[D] | acc[16] || Carry[NSEG*D] | E[NSEG*D] | muw[D]
  //                                  || dchunk[CCH] | cumdec[CCH] | Aseg[NSEG]
  float* ws      = (float*)d_ws;
  float* SL      = ws;
  float* contrib = SL + (size_t)CCH * D_DIM;
  float* acc     = contrib + D_DIM;
  float* Carry   = acc + 16;
  float* E       = Carry + (size_t)NSEG * D_DIM;
  float* muw     = E + (size_t)NSEG * D_DIM;
  float* dchunk  = muw + D_DIM;
  float* cumdec  = dchunk + CCH;
  float* Aseg    = cumdec + CCH;

  size_t zero_floats = (size_t)CCH * D_DIM + D_DIM + 16;
  hipMemsetAsync(d_ws, 0, zero_floats * sizeof(float), stream);

  k_small     <<<138, 256, 0, stream>>>(t_events, marks, Tp, log_mu, muw,
                                        contrib, SL, dchunk, cumdec, Aseg, acc);
  k_scan_local<<<NSEG*8, 256, 0, stream>>>(SL, dchunk, Carry);
  k_scan_carry<<<8, 256, 0, stream>>>(Carry, Aseg, E);
  k_events    <<<CCH, 256, 0, stream>>>(t_events, marks, log_alpha, muw,
                                        SL, E, cumdec, acc);
  k_int_alpha <<<512, 256, 0, stream>>>(log_alpha, contrib, acc);
  k_final     <<<1, 1, 0, stream>>>(acc, Tp, out);
}

// Round 3
// 120.108 us; speedup vs baseline: 1.4131x; 1.0559x over previous
//
#include <hip/hip_runtime.h>
#include <math.h>

#define D_DIM 2048
#define M_EV  16384
#define LCH   32
#define CCH   (M_EV / LCH)      // 512 chunks
#define SEG   32                // chunks per scan segment
#define NSEG  (CCH / SEG)       // 16 segments
#define BETA  1.0f

__device__ __forceinline__ float softplus_f(float x){
  float e = __expf(-fabsf(x));
  return fmaxf(x, 0.0f) + __logf(1.0f + e);
}

// T_max arrives as a 1-element array; decode int-vs-float defensively.
__device__ __forceinline__ float decode_T(const void* p){
  unsigned bits = *(const unsigned*)p;
  float fv = __uint_as_float(bits);
  return (fv >= 1e-3f && fv <= 1e7f) ? fv : (float)(int)bits;
}

__device__ __forceinline__ float wave_red(float v){
  #pragma unroll
  for (int o = 32; o > 0; o >>= 1) v += __shfl_down(v, o);
  return v;
}

// Fused small-work kernel. Block ranges:
//   [0,8)     : muw[j] = softplus(log_mu)+eps ; acc[2] += sum(mu)
//   [8,72)    : contrib[m_i] += 1-exp(-beta*(T-t_i))
//   [72,136)  : Lsum scatter: SL[c][m_i] += exp(-beta*(t_{(c+1)L}-t_i))
//   [136,138) : dchunk/cumdec per chunk (+ Aseg per segment in block 136)
__global__ void k_small(const float* __restrict__ t, const int* __restrict__ m,
                        const void* Tp, const float* __restrict__ log_mu,
                        float* __restrict__ muw, float* __restrict__ contrib,
                        float* __restrict__ SL, float* __restrict__ dchunk,
                        float* __restrict__ cumdec, float* __restrict__ Aseg,
                        float* __restrict__ acc){
  const int b = blockIdx.x, tid = threadIdx.x;
  if (b < 8){
    int j = b*256 + tid;
    float v = softplus_f(log_mu[j]) + 1e-6f;
    muw[j] = v;
    float s = wave_red(v);
    if ((tid & 63) == 0) atomicAdd(&acc[2], s);
  } else if (b < 72){
    int i = (b-8)*256 + tid;
    float T = decode_T(Tp);
    float v = 1.0f - __expf(-BETA * (T - t[i]));
    atomicAdd(&contrib[m[i]], v);
  } else if (b < 136){
    int i = (b-72)*256 + tid;
    int c = i >> 5;
    if (c < CCH - 1){                       // last chunk's carry is unused
      float tn = t[(c+1)*LCH];
      float v = __expf(-BETA * (tn - t[i]));
      atomicAdd(&SL[(size_t)c * D_DIM + m[i]], v);
    }
  } else {
    int c = (b-136)*256 + tid;              // c in [0,512)
    float tc = t[c*LCH];
    dchunk[c] = (c < CCH-1) ? __expf(-BETA * (t[(c+1)*LCH] - tc)) : 1.0f;
    int s0c = (c >> 5) << 5;                // segment-start chunk
    cumdec[c] = __expf(-BETA * (tc - t[s0c*LCH]));
    if (b == 136 && tid < NSEG){
      int s = tid;
      Aseg[s] = (s < NSEG-1)
        ? __expf(-BETA * (t[(s+1)*SEG*LCH] - t[s*SEG*LCH])) : 1.0f;
    }
  }
}

// Local exclusive scan within each segment (in-place), carry-out per segment.
__global__ void k_scan_local(float* __restrict__ SL,
                             const float* __restrict__ dchunk,
                             float* __restrict__ Carry){
  const int tid = threadIdx.x;
  const int seg = blockIdx.x >> 3, jb = blockIdx.x & 7;
  const int j = jb*256 + tid;
  const int c0 = seg * SEG;
  const size_t base = (size_t)c0 * D_DIM + j;
  float u = 0.f;
  float cur[4], nxt[4];
  #pragma unroll
  for (int q = 0; q < 4; ++q) cur[q] = SL[base + (size_t)q * D_DIM];
  for (int g = 0; g < SEG; g += 4){
    #pragma unroll
    for (int q = 0; q < 4; ++q)
      nxt[q] = (g+4 < SEG) ? SL[base + (size_t)(g+4+q) * D_DIM] : 0.f;
    #pragma unroll
    for (int q = 0; q < 4; ++q){
      int c = c0 + g + q;
      float l = cur[q];
      SL[(size_t)c * D_DIM + j] = u;
      u = fmaf(dchunk[c], u, l);
    }
    #pragma unroll
    for (int q = 0; q < 4; ++q) cur[q] = nxt[q];
  }
  Carry[(size_t)seg * D_DIM + j] = u;
}

// Scan segment carries: E[s][j] = state entering segment s.
__global__ void k_scan_carry(const float* __restrict__ Carry,
                             const float* __restrict__ Aseg,
                             float* __restrict__ E){
  const int j = blockIdx.x*256 + threadIdx.x;
  float cr[NSEG];
  #pragma unroll
  for (int s = 0; s < NSEG; ++s) cr[s] = Carry[(size_t)s * D_DIM + j];
  float e = 0.f;
  #pragma unroll
  for (int s = 0; s < NSEG; ++s){
    E[(size_t)s * D_DIM + j] = e;
    e = fmaf(Aseg[s], e, cr[s]);
  }
}

// sA = softplus(log_alpha) materialized once; integral term accumulated in
// the same pass (reads every element anyway): acc[1] += sum sA[d,j]*contrib[j].
__global__ void k_alpha(const float* __restrict__ la,
                        const float* __restrict__ contrib,
                        float* __restrict__ sA, float* __restrict__ acc){
  const int nthreads = gridDim.x * blockDim.x;      // 131072
  int tid = blockIdx.x * blockDim.x + threadIdx.x;
  const float4* la4 = (const float4*)la;
  float4* sA4 = (float4*)sA;
  float p = 0.f;
  #pragma unroll
  for (int u = 0; u < 8; ++u){
    int i4 = tid + u * nthreads;
    float4 x = la4[i4];
    float4 sp;
    sp.x = softplus_f(x.x); sp.y = softplus_f(x.y);
    sp.z = softplus_f(x.z); sp.w = softplus_f(x.w);
    sA4[i4] = sp;
    int col = (i4 * 4) & (D_DIM - 1);
    p = fmaf(sp.x, contrib[col+0], p);
    p = fmaf(sp.y, contrib[col+1], p);
    p = fmaf(sp.z, contrib[col+2], p);
    p = fmaf(sp.w, contrib[col+3], p);
  }
  __shared__ float red[4];
  float w = wave_red(p);
  int lane = threadIdx.x & 63, wid = threadIdx.x >> 6;
  if (lane == 0) red[wid] = w;
  __syncthreads();
  if (threadIdx.x == 0) atomicAdd(&acc[1], red[0]+red[1]+red[2]+red[3]);
}

// One block per chunk. S in registers (thread owns cols [8t,8t+8)).
// Inner loop is pure FMA on precomputed sA rows; depth-2 row prefetch.
__global__ __launch_bounds__(256) void k_events(
    const float* __restrict__ t, const int* __restrict__ m,
    const float* __restrict__ sA, const float* __restrict__ muw,
    const float* __restrict__ SL, const float* __restrict__ E,
    const float* __restrict__ cumdec, float* __restrict__ acc){
  __shared__ float tl[LCH];
  __shared__ int   ml[LCH];
  __shared__ float red[LCH][4];
  const int tid = threadIdx.x;
  const int c = blockIdx.x;
  const int seg = c >> 5;
  const float cd = cumdec[c];

  const float4* sp = (const float4*)(SL + (size_t)c  * D_DIM + tid*8);
  const float4* ep = (const float4*)(E  + (size_t)seg * D_DIM + tid*8);
  float4 s0 = sp[0], s1 = sp[1];
  float4 e0 = ep[0], e1 = ep[1];
  s0.x = fmaf(e0.x, cd, s0.x); s0.y = fmaf(e0.y, cd, s0.y);
  s0.z = fmaf(e0.z, cd, s0.z); s0.w = fmaf(e0.w, cd, s0.w);
  s1.x = fmaf(e1.x, cd, s1.x); s1.y = fmaf(e1.y, cd, s1.y);
  s1.z = fmaf(e1.z, cd, s1.z); s1.w = fmaf(e1.w, cd, s1.w);

  if (tid < LCH){ tl[tid] = t[c*LCH + tid]; ml[tid] = m[c*LCH + tid]; }
  __syncthreads();

  const int lane = tid & 63, wid = tid >> 6;
  const int colb = tid * 8;

  // depth-2 prefetch pipeline
  const float* P0 = sA + (size_t)ml[0] * D_DIM + colb;
  float4 a0 = *(const float4*)P0, a1 = *(const float4*)(P0 + 4);
  const float* P1 = sA + (size_t)ml[1] * D_DIM + colb;
  float4 b0 = *(const float4*)P1, b1 = *(const float4*)(P1 + 4);

  #pragma unroll 1
  for (int k = 0; k < LCH; ++k){
    const int d = ml[k];
    const int kn = (k + 2 < LCH) ? k + 2 : LCH - 1;
    const float* Pn = sA + (size_t)ml[kn] * D_DIM + colb;
    float4 c0v = *(const float4*)Pn, c1v = *(const float4*)(Pn + 4);

    const float dec = (k == 0) ? 1.0f : __expf(-BETA * (tl[k] - tl[k-1]));
    s0.x *= dec; s0.y *= dec; s0.z *= dec; s0.w *= dec;
    s1.x *= dec; s1.y *= dec; s1.z *= dec; s1.w *= dec;

    float p = 0.f;
    p = fmaf(a0.x, s0.x, p); p = fmaf(a0.y, s0.y, p);
    p = fmaf(a0.z, s0.z, p); p = fmaf(a0.w, s0.w, p);
    p = fmaf(a1.x, s1.x, p); p = fmaf(a1.y, s1.y, p);
    p = fmaf(a1.z, s1.z, p); p = fmaf(a1.w, s1.w, p);

    if ((d >> 3) == tid){                     // self-excitation bump (owner)
      int r = d & 7;
      s0.x += (r==0) ? 1.f : 0.f; s0.y += (r==1) ? 1.f : 0.f;
      s0.z += (r==2) ? 1.f : 0.f; s0.w += (r==3) ? 1.f : 0.f;
      s1.x += (r==4) ? 1.f : 0.f; s1.y += (r==5) ? 1.f : 0.f;
      s1.z += (r==6) ? 1.f : 0.f; s1.w += (r==7) ? 1.f : 0.f;
    }

    float w = wave_red(p);
    if (lane == 0) red[k][wid] = w;           // no barrier until the end

    a0 = b0; a1 = b1; b0 = c0v; b1 = c1v;
  }

  __syncthreads();
  float lg = 0.f;
  if (tid < LCH){
    float lam = muw[ml[tid]] + red[tid][0] + red[tid][1]
                             + red[tid][2] + red[tid][3];
    lg = __logf(lam + 1e-8f);
  }
  if (tid < 64){
    float w = wave_red(lg);
    if (tid == 0) atomicAdd(&acc[0], w);
  }
}

__global__ void k_final(const float* __restrict__ acc, const void* Tp,
                        float* __restrict__ out){
  float T = decode_T(Tp);
  out[0] = acc[0] - (T * acc[2] + acc[1] * (1.0f / BETA));
}

extern "C" void kernel_launch(void* const* d_in, const int* in_sizes, int n_in,
                              void* d_out, int out_size, void* d_ws, size_t ws_size,
                              hipStream_t stream) {
  const float* t_events  = (const float*)d_in[0];
  const int*   marks     = (const int*)  d_in[1];
  const void*  Tp        =               d_in[2];
  const float* log_mu    = (const float*)d_in[3];
  const float* log_alpha = (const float*)d_in[4];
  float* out = (float*)d_out;

  // ws layout (floats), zeroed region first:
  // SL[CCH*D] | contrib[D] | acc[16] || Carry[NSEG*D] | E[NSEG*D] | muw[D]
  //   | dchunk[CCH] | cumdec[CCH] | Aseg[NSEG] | sA[D*D]
  float* ws      = (float*)d_ws;
  float* SL      = ws;
  float* contrib = SL + (size_t)CCH * D_DIM;
  float* acc     = contrib + D_DIM;
  float* Carry   = acc + 16;
  float* E       = Carry + (size_t)NSEG * D_DIM;
  float* muw     = E + (size_t)NSEG * D_DIM;
  float* dchunk  = muw + D_DIM;
  float* cumdec  = dchunk + CCH;
  float* Aseg    = cumdec + CCH;
  float* sA      = Aseg + NSEG;

  size_t zero_floats = (size_t)CCH * D_DIM + D_DIM + 16;
  hipMemsetAsync(d_ws, 0, zero_floats * sizeof(float), stream);

  k_small     <<<138, 256, 0, stream>>>(t_events, marks, Tp, log_mu, muw,
                                        contrib, SL, dchunk, cumdec, Aseg, acc);
  k_scan_local<<<NSEG*8, 256, 0, stream>>>(SL, dchunk, Carry);
  k_scan_carry<<<8, 256, 0, stream>>>(Carry, Aseg, E);
  k_alpha     <<<512, 256, 0, stream>>>(log_alpha, contrib, sA, acc);
  k_events    <<<CCH, 256, 0, stream>>>(t_events, marks, sA, muw,
                                        SL, E, cumdec, acc);
  k_final     <<<1, 1, 0, stream>>>(acc, Tp, out);
}

// Round 4
// 116.727 us; speedup vs baseline: 1.4540x; 1.0290x over previous
//
#include <hip/hip_runtime.h>
#include <math.h>

#define D_DIM 2048
#define M_EV  16384
#define LCH   32
#define CCH   (M_EV / LCH)      // 512 chunks
#define SEG   32                // chunks per scan segment
#define NSEG  (CCH / SEG)       // 16 segments
#define BETA  1.0f

__device__ __forceinline__ float softplus_f(float x){
  float e = __expf(-fabsf(x));
  return fmaxf(x, 0.0f) + __logf(1.0f + e);
}

// float -> bf16 (RNE); inputs are finite non-negative here.
__device__ __forceinline__ unsigned short f2bf(float f){
  unsigned b = __float_as_uint(f);
  return (unsigned short)((b + 0x7FFFu + ((b >> 16) & 1u)) >> 16);
}
__device__ __forceinline__ float bf2f(unsigned short u){
  return __uint_as_float(((unsigned)u) << 16);
}

// T_max arrives as a 1-element array; decode int-vs-float defensively.
__device__ __forceinline__ float decode_T(const void* p){
  unsigned bits = *(const unsigned*)p;
  float fv = __uint_as_float(bits);
  return (fv >= 1e-3f && fv <= 1e7f) ? fv : (float)(int)bits;
}

__device__ __forceinline__ float wave_red(float v){
  #pragma unroll
  for (int o = 32; o > 0; o >>= 1) v += __shfl_down(v, o);
  return v;
}

// Fused small-work kernel. Block ranges:
//   [0,8)     : muw[j] = softplus(log_mu)+eps ; acc[2] += sum(mu)
//   [8,72)    : contrib[m_i] += 1-exp(-beta*(T-t_i))
//   [72,136)  : Lsum scatter: SL[c][m_i] += exp(-beta*(t_{(c+1)L}-t_i))
//   [136,138) : dchunk/cumdec per chunk (+ Aseg per segment in block 136)
__global__ void k_small(const float* __restrict__ t, const int* __restrict__ m,
                        const void* Tp, const float* __restrict__ log_mu,
                        float* __restrict__ muw, float* __restrict__ contrib,
                        float* __restrict__ SL, float* __restrict__ dchunk,
                        float* __restrict__ cumdec, float* __restrict__ Aseg,
                        float* __restrict__ acc){
  const int b = blockIdx.x, tid = threadIdx.x;
  if (b < 8){
    int j = b*256 + tid;
    float v = softplus_f(log_mu[j]) + 1e-6f;
    muw[j] = v;
    float s = wave_red(v);
    if ((tid & 63) == 0) atomicAdd(&acc[2], s);
  } else if (b < 72){
    int i = (b-8)*256 + tid;
    float T = decode_T(Tp);
    float v = 1.0f - __expf(-BETA * (T - t[i]));
    atomicAdd(&contrib[m[i]], v);
  } else if (b < 136){
    int i = (b-72)*256 + tid;
    int c = i >> 5;
    if (c < CCH - 1){                       // last chunk's carry is unused
      float tn = t[(c+1)*LCH];
      float v = __expf(-BETA * (tn - t[i]));
      atomicAdd(&SL[(size_t)c * D_DIM + m[i]], v);
    }
  } else {
    int c = (b-136)*256 + tid;              // c in [0,512)
    float tc = t[c*LCH];
    dchunk[c] = (c < CCH-1) ? __expf(-BETA * (t[(c+1)*LCH] - tc)) : 1.0f;
    int s0c = (c >> 5) << 5;                // segment-start chunk
    cumdec[c] = __expf(-BETA * (tc - t[s0c*LCH]));
    if (b == 136 && tid < NSEG){
      int s = tid;
      Aseg[s] = (s < NSEG-1)
        ? __expf(-BETA * (t[(s+1)*SEG*LCH] - t[s*SEG*LCH])) : 1.0f;
    }
  }
}

// Local exclusive scan within each segment (in-place), carry-out per segment.
__global__ void k_scan_local(float* __restrict__ SL,
                             const float* __restrict__ dchunk,
                             float* __restrict__ Carry){
  const int tid = threadIdx.x;
  const int seg = blockIdx.x >> 3, jb = blockIdx.x & 7;
  const int j = jb*256 + tid;
  const int c0 = seg * SEG;
  const size_t base = (size_t)c0 * D_DIM + j;
  float u = 0.f;
  float cur[4], nxt[4];
  #pragma unroll
  for (int q = 0; q < 4; ++q) cur[q] = SL[base + (size_t)q * D_DIM];
  for (int g = 0; g < SEG; g += 4){
    #pragma unroll
    for (int q = 0; q < 4; ++q)
      nxt[q] = (g+4 < SEG) ? SL[base + (size_t)(g+4+q) * D_DIM] : 0.f;
    #pragma unroll
    for (int q = 0; q < 4; ++q){
      int c = c0 + g + q;
      float l = cur[q];
      SL[(size_t)c * D_DIM + j] = u;
      u = fmaf(dchunk[c], u, l);
    }
    #pragma unroll
    for (int q = 0; q < 4; ++q) cur[q] = nxt[q];
  }
  Carry[(size_t)seg * D_DIM + j] = u;
}

// Scan segment carries: E[s][j] = state entering segment s.
__global__ void k_scan_carry(const float* __restrict__ Carry,
                             const float* __restrict__ Aseg,
                             float* __restrict__ E){
  const int j = blockIdx.x*256 + threadIdx.x;
  float cr[NSEG];
  #pragma unroll
  for (int s = 0; s < NSEG; ++s) cr[s] = Carry[(size_t)s * D_DIM + j];
  float e = 0.f;
  #pragma unroll
  for (int s = 0; s < NSEG; ++s){
    E[(size_t)s * D_DIM + j] = e;
    e = fmaf(Aseg[s], e, cr[s]);
  }
}

// sA = bf16(softplus(log_alpha)) materialized once; integral term accumulated
// in the same pass (fp32): acc[1] += sum softplus(la[d,j])*contrib[j].
__global__ void k_alpha(const float* __restrict__ la,
                        const float* __restrict__ contrib,
                        unsigned short* __restrict__ sA,
                        float* __restrict__ acc){
  const int nthreads = gridDim.x * blockDim.x;      // 131072
  int tid = blockIdx.x * blockDim.x + threadIdx.x;
  const float4* la4 = (const float4*)la;
  ushort4* sA4 = (ushort4*)sA;
  float p = 0.f;
  #pragma unroll
  for (int u = 0; u < 8; ++u){
    int i4 = tid + u * nthreads;
    float4 x = la4[i4];
    float4 sp;
    sp.x = softplus_f(x.x); sp.y = softplus_f(x.y);
    sp.z = softplus_f(x.z); sp.w = softplus_f(x.w);
    ushort4 h;
    h.x = f2bf(sp.x); h.y = f2bf(sp.y); h.z = f2bf(sp.z); h.w = f2bf(sp.w);
    sA4[i4] = h;
    int col = (i4 * 4) & (D_DIM - 1);
    p = fmaf(sp.x, contrib[col+0], p);
    p = fmaf(sp.y, contrib[col+1], p);
    p = fmaf(sp.z, contrib[col+2], p);
    p = fmaf(sp.w, contrib[col+3], p);
  }
  __shared__ float red[4];
  float w = wave_red(p);
  int lane = threadIdx.x & 63, wid = threadIdx.x >> 6;
  if (lane == 0) red[wid] = w;
  __syncthreads();
  if (threadIdx.x == 0) atomicAdd(&acc[1], red[0]+red[1]+red[2]+red[3]);
}

// One block (512 thr) per chunk. Thread owns 4 cols of S in registers.
// bf16 rows, depth-4 prefetch, per-event decay precomputed in LDS,
// no barrier inside the event loop.
__global__ __launch_bounds__(512) void k_events(
    const float* __restrict__ t, const int* __restrict__ m,
    const unsigned short* __restrict__ sA, const float* __restrict__ muw,
    const float* __restrict__ SL, const float* __restrict__ E,
    const float* __restrict__ cumdec, float* __restrict__ acc){
  __shared__ int   ml[LCH];
  __shared__ float decs[LCH];
  __shared__ float red[LCH][8];
  const int tid = threadIdx.x;          // 0..511
  const int c = blockIdx.x;
  const int seg = c >> 5;
  const float cd = cumdec[c];

  const float4 sv = *(const float4*)(SL + (size_t)c  * D_DIM + tid*4);
  const float4 ev = *(const float4*)(E  + (size_t)seg * D_DIM + tid*4);
  float4 s;
  s.x = fmaf(ev.x, cd, sv.x); s.y = fmaf(ev.y, cd, sv.y);
  s.z = fmaf(ev.z, cd, sv.z); s.w = fmaf(ev.w, cd, sv.w);

  if (tid < LCH){
    ml[tid] = m[c*LCH + tid];
    float tk = t[c*LCH + tid];
    float tp = (tid == 0) ? tk : t[c*LCH + tid - 1];
    decs[tid] = __expf(-BETA * (tk - tp));   // ==1 for k==0
  }
  __syncthreads();

  const int lane = tid & 63, wid = tid >> 6;
  const int colb = tid * 4;

  ushort4 pf0 = *(const ushort4*)(sA + (size_t)ml[0] * D_DIM + colb);
  ushort4 pf1 = *(const ushort4*)(sA + (size_t)ml[1] * D_DIM + colb);
  ushort4 pf2 = *(const ushort4*)(sA + (size_t)ml[2] * D_DIM + colb);
  ushort4 pf3 = *(const ushort4*)(sA + (size_t)ml[3] * D_DIM + colb);

#define STAGE(Q) {                                                          \
    const int kk = k + (Q);                                                 \
    const int d = ml[kk];                                                   \
    const int kn = (kk + 4 < LCH) ? kk + 4 : LCH - 1;                       \
    ushort4 nx = *(const ushort4*)(sA + (size_t)ml[kn] * D_DIM + colb);     \
    const float dec = decs[kk];                                             \
    s.x *= dec; s.y *= dec; s.z *= dec; s.w *= dec;                         \
    float p = 0.f;                                                          \
    p = fmaf(bf2f(pf##Q.x), s.x, p);                                        \
    p = fmaf(bf2f(pf##Q.y), s.y, p);                                        \
    p = fmaf(bf2f(pf##Q.z), s.z, p);                                        \
    p = fmaf(bf2f(pf##Q.w), s.w, p);                                        \
    if ((d >> 2) == tid){                                                   \
      int r = d & 3;                                                        \
      s.x += (r==0) ? 1.f : 0.f; s.y += (r==1) ? 1.f : 0.f;                 \
      s.z += (r==2) ? 1.f : 0.f; s.w += (r==3) ? 1.f : 0.f;                 \
    }                                                                       \
    float w = wave_red(p);                                                  \
    if (lane == 0) red[kk][wid] = w;                                        \
    pf##Q = nx;                                                             \
  }

  for (int k = 0; k < LCH; k += 4){
    STAGE(0) STAGE(1) STAGE(2) STAGE(3)
  }
#undef STAGE

  __syncthreads();
  float lg = 0.f;
  if (tid < LCH){
    const float* r = red[tid];
    float lam = muw[ml[tid]] + ((r[0]+r[1])+(r[2]+r[3]))
                             + ((r[4]+r[5])+(r[6]+r[7]));
    lg = __logf(lam + 1e-8f);
  }
  if (tid < 64){
    float w = wave_red(lg);
    if (tid == 0) atomicAdd(&acc[0], w);
  }
}

__global__ void k_final(const float* __restrict__ acc, const void* Tp,
                        float* __restrict__ out){
  float T = decode_T(Tp);
  out[0] = acc[0] - (T * acc[2] + acc[1] * (1.0f / BETA));
}

extern "C" void kernel_launch(void* const* d_in, const int* in_sizes, int n_in,
                              void* d_out, int out_size, void* d_ws, size_t ws_size,
                              hipStream_t stream) {
  const float* t_events  = (const float*)d_in[0];
  const int*   marks     = (const int*)  d_in[1];
  const void*  Tp        =               d_in[2];
  const float* log_mu    = (const float*)d_in[3];
  const float* log_alpha = (const float*)d_in[4];
  float* out = (float*)d_out;

  // ws layout (floats), zeroed region first:
  // SL[CCH*D] | contrib[D] | acc[16] || Carry[NSEG*D] | E[NSEG*D] | muw[D]
  //   | dchunk[CCH] | cumdec[CCH] | Aseg[NSEG] | sA[D*D bf16]
  float* ws      = (float*)d_ws;
  float* SL      = ws;
  float* contrib = SL + (size_t)CCH * D_DIM;
  float* acc     = contrib + D_DIM;
  float* Carry   = acc + 16;
  float* E       = Carry + (size_t)NSEG * D_DIM;
  float* muw     = E + (size_t)NSEG * D_DIM;
  float* dchunk  = muw + D_DIM;
  float* cumdec  = dchunk + CCH;
  float* Aseg    = cumdec + CCH;
  unsigned short* sA = (unsigned short*)(Aseg + NSEG);  // 16B-aligned offset

  size_t zero_floats = (size_t)CCH * D_DIM + D_DIM + 16;
  hipMemsetAsync(d_ws, 0, zero_floats * sizeof(float), stream);

  k_small     <<<138, 256, 0, stream>>>(t_events, marks, Tp, log_mu, muw,
                                        contrib, SL, dchunk, cumdec, Aseg, acc);
  k_scan_local<<<NSEG*8, 256, 0, stream>>>(SL, dchunk, Carry);
  k_scan_carry<<<8, 256, 0, stream>>>(Carry, Aseg, E);
  k_alpha     <<<512, 256, 0, stream>>>(log_alpha, contrib, sA, acc);
  k_events    <<<CCH, 512, 0, stream>>>(t_events, marks, sA, muw,
                                        SL, E, cumdec, acc);
  k_final     <<<1, 1, 0, stream>>>(acc, Tp, out);
}